// Round 1
// baseline (1818.117 us; speedup 1.0000x reference)
//
#include <hip/hip_runtime.h>

#define B_   16
#define NH   16
#define HS   128
#define C_   2048
#define TP   4095
#define TT   4096

// ---------------- init: write biases into qkv (ws) and y (out) ----------------
__global__ __launch_bounds__(256) void init_bias(const float* __restrict__ b_attn,
                                                 const float* __restrict__ b_proj,
                                                 float* __restrict__ qkv,
                                                 float* __restrict__ y)
{
    int i = blockIdx.x * 256 + threadIdx.x;
    if (i < B_ * 3 * C_) qkv[i] = b_attn[i % (3 * C_)];
    if (i < B_ * C_)     y[i]   = b_proj[i % C_];
}

// ---------------- QKV projection: [16,2048] @ [2048,6144], split-K atomics ----
__global__ __launch_bounds__(256) void gemm_qkv(const float* __restrict__ x,
                                                const float* __restrict__ W,
                                                float* __restrict__ qkv)
{
    const int col = blockIdx.x * 256 + threadIdx.x;   // 0..6143
    const int k0  = blockIdx.y * 256;                 // 8 slices of 256
    float acc[B_];
#pragma unroll
    for (int b = 0; b < B_; ++b) acc[b] = 0.f;
#pragma unroll 4
    for (int k = k0; k < k0 + 256; ++k) {
        const float w = W[(size_t)k * (3 * C_) + col];
#pragma unroll
        for (int b = 0; b < B_; ++b)
            acc[b] = fmaf(x[b * C_ + k], w, acc[b]);
    }
#pragma unroll
    for (int b = 0; b < B_; ++b)
        atomicAdd(&qkv[b * (3 * C_) + col], acc[b]);
}

// ---------------- output projection: [16,2048] @ [2048,2048], split-K --------
__global__ __launch_bounds__(256) void gemm_proj(const float* __restrict__ ya,
                                                 const float* __restrict__ W,
                                                 float* __restrict__ out)
{
    const int col = blockIdx.x * 256 + threadIdx.x;   // 0..2047
    const int k0  = blockIdx.y * 128;                 // 16 slices of 128
    float acc[B_];
#pragma unroll
    for (int b = 0; b < B_; ++b) acc[b] = 0.f;
#pragma unroll 4
    for (int k = k0; k < k0 + 128; ++k) {
        const float w = W[(size_t)k * C_ + col];
#pragma unroll
        for (int b = 0; b < B_; ++b)
            acc[b] = fmaf(ya[b * C_ + k], w, acc[b]);
    }
#pragma unroll
    for (int b = 0; b < B_; ++b)
        atomicAdd(&out[b * C_ + col], acc[b]);
}

// ---------------- fused attention + requantization ---------------------------
// one block per (b,h); 1024 threads = 16 waves = 32 half-wave slots;
// slot s streams tokens t = s, s+32, ... with online softmax; each half-wave
// lane owns 4 dims (int4/float4 per row). Requant fused into the same pass.
__global__ __launch_bounds__(1024) void attn_requant(
    const float* __restrict__ qkv,
    const int*   __restrict__ pkq, const float* __restrict__ pks,
    const int*   __restrict__ pvq, const float* __restrict__ pvs,
    float* __restrict__ out_kq, float* __restrict__ out_ks,
    float* __restrict__ out_vq, float* __restrict__ out_vs,
    float* __restrict__ y_att)
{
    const int bh   = blockIdx.x;            // 0..255
    const int b    = bh >> 4, h = bh & 15;
    const int tid  = threadIdx.x;
    const int lane = tid & 63;
    const int wave = tid >> 6;              // 0..15
    const int half = lane >> 5;             // 0/1
    const int slot = wave * 2 + half;       // 0..31
    const int l    = lane & 31;
    const int j0   = l * 4;

    const float invs = 0.08838834764831845f;   // 1/sqrt(128)
    const float* qrow = qkv + b * (3 * C_) + h * HS;
    const float4 qv = *(const float4*)(qrow + j0);
    const float q0 = qv.x * invs, q1 = qv.y * invs, q2 = qv.z * invs, q3 = qv.w * invs;
    const float* knew = qkv + b * (3 * C_) + C_     + h * HS;
    const float* vnew = qkv + b * (3 * C_) + 2 * C_ + h * HS;

    const size_t cbase = (size_t)bh * TP * HS;   // past cache row base
    const size_t obase = (size_t)bh * TT * HS;   // quant output row base

    float m = -1e30f, lsum = 0.f;
    float a0 = 0.f, a1 = 0.f, a2 = 0.f, a3 = 0.f;

#pragma unroll 2
    for (int i = 0; i < TT / 32; ++i) {
        const int t = i * 32 + slot;
        float kf0, kf1, kf2, kf3, vf0, vf1, vf2, vf3;
        if (t < TP) {
            const int4 ki = *(const int4*)(pkq + cbase + (size_t)t * HS + j0);
            const int4 vi = *(const int4*)(pvq + cbase + (size_t)t * HS + j0);
            const float sk = pks[bh * TP + t];
            const float sv = pvs[bh * TP + t];
            kf0 = (float)ki.x * sk; kf1 = (float)ki.y * sk;
            kf2 = (float)ki.z * sk; kf3 = (float)ki.w * sk;
            vf0 = (float)vi.x * sv; vf1 = (float)vi.y * sv;
            vf2 = (float)vi.z * sv; vf3 = (float)vi.w * sv;
        } else {  // new token (t == 4095): from QKV projection
            const float4 kk = *(const float4*)(knew + j0);
            const float4 vv = *(const float4*)(vnew + j0);
            kf0 = kk.x; kf1 = kk.y; kf2 = kk.z; kf3 = kk.w;
            vf0 = vv.x; vf1 = vv.y; vf2 = vv.z; vf3 = vv.w;
        }
        // per-row maxabs (half-wave reduce over 32 lanes x 4 dims)
        float mk = fmaxf(fmaxf(fabsf(kf0), fabsf(kf1)), fmaxf(fabsf(kf2), fabsf(kf3)));
        float mv = fmaxf(fmaxf(fabsf(vf0), fabsf(vf1)), fmaxf(fabsf(vf2), fabsf(vf3)));
#pragma unroll
        for (int d = 16; d; d >>= 1) {
            mk = fmaxf(mk, __shfl_xor(mk, d));
            mv = fmaxf(mv, __shfl_xor(mv, d));
        }
        const float rk = mk > 0.f ? 127.0f / mk : 0.f;
        const float rv = mv > 0.f ? 127.0f / mv : 0.f;
        const float4 kqo = make_float4(rintf(kf0 * rk), rintf(kf1 * rk),
                                       rintf(kf2 * rk), rintf(kf3 * rk));
        const float4 vqo = make_float4(rintf(vf0 * rv), rintf(vf1 * rv),
                                       rintf(vf2 * rv), rintf(vf3 * rv));
        *(float4*)(out_kq + obase + (size_t)t * HS + j0) = kqo;
        *(float4*)(out_vq + obase + (size_t)t * HS + j0) = vqo;
        if (l == 0) {
            out_ks[bh * TT + t] = mk * (1.0f / 127.0f);
            out_vs[bh * TT + t] = mv * (1.0f / 127.0f);
        }
        // attention score (q pre-scaled by 1/sqrt(hs))
        float sc = q0 * kf0 + q1 * kf1 + q2 * kf2 + q3 * kf3;
#pragma unroll
        for (int d = 16; d; d >>= 1) sc += __shfl_xor(sc, d);
        // online softmax update
        const float mn   = fmaxf(m, sc);
        const float corr = __expf(m - mn);   // m=-1e30 first iter -> 0
        const float p    = __expf(sc - mn);
        lsum = lsum * corr + p;
        a0 = a0 * corr + p * vf0;
        a1 = a1 * corr + p * vf1;
        a2 = a2 * corr + p * vf2;
        a3 = a3 * corr + p * vf3;
        m = mn;
    }

    // ---- combine 32 slots ----
    __shared__ float sacc[32][HS + 1];
    __shared__ float sm[32], sl[32], sw[32];
    __shared__ float sLtot;
    sacc[slot][j0 + 0] = a0;
    sacc[slot][j0 + 1] = a1;
    sacc[slot][j0 + 2] = a2;
    sacc[slot][j0 + 3] = a3;
    if (l == 0) { sm[slot] = m; sl[slot] = lsum; }
    __syncthreads();
    if (tid < 32) {
        float mg = sm[tid];
#pragma unroll
        for (int d = 16; d; d >>= 1) mg = fmaxf(mg, __shfl_xor(mg, d));
        const float w  = __expf(sm[tid] - mg);
        float lw = sl[tid] * w;
#pragma unroll
        for (int d = 16; d; d >>= 1) lw += __shfl_xor(lw, d);
        sw[tid] = w;
        if (tid == 0) sLtot = lw;
    }
    __syncthreads();
    if (tid < HS) {
        float sum = 0.f;
#pragma unroll
        for (int s = 0; s < 32; ++s) sum += sacc[s][tid] * sw[s];
        y_att[bh * HS + tid] = sum / sLtot;
    }
}

extern "C" void kernel_launch(void* const* d_in, const int* in_sizes, int n_in,
                              void* d_out, int out_size, void* d_ws, size_t ws_size,
                              hipStream_t stream)
{
    const float* x      = (const float*)d_in[0];
    const float* W_attn = (const float*)d_in[1];
    const float* b_attn = (const float*)d_in[2];
    const float* W_proj = (const float*)d_in[3];
    const float* b_proj = (const float*)d_in[4];
    const int*   pkq    = (const int*)  d_in[5];
    const float* pks    = (const float*)d_in[6];
    const int*   pvq    = (const int*)  d_in[7];
    const float* pvs    = (const float*)d_in[8];

    float* out = (float*)d_out;
    // output layout (floats): y | k_quant | k_scale | v_quant | v_scale
    const size_t N_Y  = (size_t)B_ * C_;            // 32768
    const size_t N_KQ = (size_t)B_ * NH * TT * HS;  // 134217728
    const size_t N_SC = (size_t)B_ * NH * TT;       // 1048576
    float* out_y  = out;
    float* out_kq = out + N_Y;
    float* out_ks = out_kq + N_KQ;
    float* out_vq = out_ks + N_SC;
    float* out_vs = out_vq + N_KQ;

    float* qkv   = (float*)d_ws;                    // [16][6144]
    float* y_att = qkv + B_ * 3 * C_;               // [256][128]

    hipLaunchKernelGGL(init_bias, dim3(384), dim3(256), 0, stream,
                       b_attn, b_proj, qkv, out_y);
    hipLaunchKernelGGL(gemm_qkv, dim3(24, 8), dim3(256), 0, stream,
                       x, W_attn, qkv);
    hipLaunchKernelGGL(attn_requant, dim3(256), dim3(1024), 0, stream,
                       qkv, pkq, pks, pvq, pvs,
                       out_kq, out_ks, out_vq, out_vs, y_att);
    hipLaunchKernelGGL(gemm_proj, dim3(8, 16), dim3(256), 0, stream,
                       y_att, W_proj, out_y);
}